// Round 10
// baseline (170.918 us; speedup 1.0000x reference)
//
#include <hip/hip_runtime.h>
#include <hip/hip_bf16.h>
#include <stdint.h>

// Shape fixed by reference: B=2, S=1024 -> M=2048; N=4096; K=4096
#define M_DIM 2048
#define N_DIM 4096
#define K_DIM 4096

#define BM 128
#define BN 128
#define BK 128            // int8 elements per K-tile = 128 B per row

#define ATILE (BM * BK)   // 16 KiB per A buffer
#define BTILE (BN * BK)
#define NT (K_DIM / BK)   // 32 K-tiles

typedef __attribute__((ext_vector_type(4)))  int   int4v;
typedef __attribute__((ext_vector_type(16))) int   int16v;
typedef __attribute__((ext_vector_type(4)))  float f32x4;

__device__ __forceinline__ void load_lds16(const void* g, void* l) {
    __builtin_amdgcn_global_load_lds(
        (const __attribute__((address_space(1))) void*)g,
        (__attribute__((address_space(3))) void*)l,
        16, 0, 0);
}

// ---------- x: fp32 [M,K] -> int8 per-row dynamic quant; sx[row] = rowmax/127 ----------
__global__ __launch_bounds__(256) void quant_x(const float* __restrict__ x,
                                               int8_t* __restrict__ Aq,
                                               float* __restrict__ sx) {
    const int row = blockIdx.x;
    const int tid = threadIdx.x;
    const float4* xr = (const float4*)(x + (size_t)row * K_DIM);

    float4 v[4];
    float mx = 0.f;
#pragma unroll
    for (int p = 0; p < 4; p++) {
        v[p] = xr[p * 256 + tid];
        mx = fmaxf(mx, fmaxf(fmaxf(fabsf(v[p].x), fabsf(v[p].y)),
                             fmaxf(fabsf(v[p].z), fabsf(v[p].w))));
    }
#pragma unroll
    for (int off = 32; off >= 1; off >>= 1)
        mx = fmaxf(mx, __shfl_xor(mx, off, 64));

    __shared__ float wmax[4];
    __shared__ float smax;
    if ((tid & 63) == 0) wmax[tid >> 6] = mx;
    __syncthreads();
    if (tid == 0) {
        float m = fmaxf(fmaxf(wmax[0], wmax[1]), fmaxf(wmax[2], wmax[3]));
        m = fmaxf(m, 1e-20f);
        smax = m;
        sx[row] = m * (1.0f / 127.0f);
    }
    __syncthreads();
    const float inv = 127.0f / smax;

    int* out = (int*)Aq + (size_t)row * (K_DIM / 4);
#pragma unroll
    for (int p = 0; p < 4; p++) {
        int q0 = (int)__builtin_rintf(v[p].x * inv);
        int q1 = (int)__builtin_rintf(v[p].y * inv);
        int q2 = (int)__builtin_rintf(v[p].z * inv);
        int q3 = (int)__builtin_rintf(v[p].w * inv);
        q0 = max(-127, min(127, q0)); q1 = max(-127, min(127, q1));
        q2 = max(-127, min(127, q2)); q3 = max(-127, min(127, q3));
        out[p * 256 + tid] = (q0 & 255) | ((q1 & 255) << 8) |
                             ((q2 & 255) << 16) | ((q3 & 255) << 24);
    }
}

// ---------- w: int32 [N,K] (values in [-128,127]) -> int8, exact narrowing ----------
__global__ __launch_bounds__(256) void cvt_w8(const int* __restrict__ w,
                                              int8_t* __restrict__ Bq) {
    size_t i = ((size_t)blockIdx.x * 256 + threadIdx.x) * 16;
    int4 a0 = *(const int4*)(w + i);
    int4 a1 = *(const int4*)(w + i + 4);
    int4 a2 = *(const int4*)(w + i + 8);
    int4 a3 = *(const int4*)(w + i + 12);
    uint4 t;
    t.x = (a0.x & 255) | ((a0.y & 255) << 8) | ((a0.z & 255) << 16) | ((a0.w & 255) << 24);
    t.y = (a1.x & 255) | ((a1.y & 255) << 8) | ((a1.z & 255) << 16) | ((a1.w & 255) << 24);
    t.z = (a2.x & 255) | ((a2.y & 255) << 8) | ((a2.z & 255) << 16) | ((a2.w & 255) << 24);
    t.w = (a3.x & 255) | ((a3.y & 255) << 8) | ((a3.z & 255) << 16) | ((a3.w & 255) << 24);
    *(uint4*)(Bq + i) = t;
}

// ---------- GEMM: C = Aq[M,K] x Bq[N,K]^T (i8 MFMA, i32 acc), epilogue dequant ----------
// r14 == r13 (infra flake retry): r4's shell byte-for-byte (the 40.7us best:
// 128x128 block, 512 thr, 8 waves 2Mx4N each 64x32 out, dbuf LDS 64 KiB,
// 2 blocks/CU, plain 2D grid, glds staging with XOR-swizzled source), with ONLY
// the MFMA shape changed: 16x16x64 i8 (16/wave/tile) -> 32x32x32 i8 (8/wave/tile).
// Rationale: 6 structurally diverse rounds all land 41-46us at MfmaUtil 28-33% --
// the barrier-convoy structure is the plateau (m233: 2-phase full structure = 28%
// of MFMA-only), and r4's 2-blk/CU co-residency covers it best. Shape is the one
// untouched axis: +12% ceiling (4404 vs 3944 TOPS), half the MFMA instructions
// (shorter serial chains), SAME ds_read count (12 b128/wave/tile) and SAME LDS
// bank-access density as the measured-zero-conflict r4 pattern.
// Fragment feeding (permutation-cancellation, as verified for 16x16): af and bf
// use the identical per-lane map {row = base + (lane&31), bytes = kstep*32 +
// (lane>>5)*16}, so any internal lane->k permutation cancels between A and B.
// Swizzle cancellation: row&7 == l32&7 (bases are multiples of 32), so phys
// cp = (kstep*2+hi) ^ (l32&7) reads back identity k-chunks.
// C/D layout (m74/m101-verified, dtype-independent): col = lane&31,
// row = (reg&3) + 8*(reg>>2) + 4*(lane>>5).

__global__ __launch_bounds__(512, 4) void gemm_bt_i8(
    const int8_t* __restrict__ A,      // [M,K] int8
    const int8_t* __restrict__ B,      // [N,K] int8
    const float*  __restrict__ sx,     // [M] row dequant scale
    const float*  __restrict__ scales, // [N]
    const float*  __restrict__ bias,   // [N]
    float* __restrict__ C)             // [M,N]
{
    __shared__ __align__(16) int8_t As[2 * ATILE];  // 32 KiB
    __shared__ __align__(16) int8_t Bs[2 * BTILE];  // 32 KiB

    const int tid  = threadIdx.x;
    const int bm   = blockIdx.y;
    const int bn   = blockIdx.x;
    const int lane = tid & 63;
    const int wave = tid >> 6;           // 0..7
    const int wm   = (wave >> 2) * 64;   // 0 or 64
    const int wn   = (wave & 3) * 32;    // 0,32,64,96
    const int l32  = lane & 31;
    const int hi   = lane >> 5;          // k-half within a 32B k-step
    const int swz  = l32 & 7;

    // Staging (r4 scheme, byte-identical): 512 thr x 16 B = 8 KiB/instr; 2 instrs
    // per 16 KiB tile. thread t -> row = t>>3 (+64 for seg1), phys colgroup = t&7;
    // global colgroup = phys ^ (row&7). LDS byte addr = 16*t (linear in tid).
    const int srow = tid >> 3;           // 0..63
    const int cgl  = (tid & 7) ^ (srow & 7);

    const int8_t* ga0 = A + (size_t)(bm * BM + srow)      * K_DIM + cgl * 16;
    const int8_t* ga1 = A + (size_t)(bm * BM + 64 + srow) * K_DIM + cgl * 16;
    const int8_t* gb0 = B + (size_t)(bn * BN + srow)      * K_DIM + cgl * 16;
    const int8_t* gb1 = B + (size_t)(bn * BN + 64 + srow) * K_DIM + cgl * 16;
    const int la0 = tid * 16;
    const int la1 = 8192 + tid * 16;

    // Prologue: stage tile 0 into buffer 0.
    load_lds16(ga0, As + la0);
    load_lds16(ga1, As + la1);
    load_lds16(gb0, Bs + la0);
    load_lds16(gb1, Bs + la1);

    int16v acc[2] = {};   // two 32x32 output tiles (rows wm+t*32, cols wn..wn+31)

    int cur = 0;
    for (int k0 = 0; k0 < K_DIM; k0 += BK, cur ^= 1) {
        __syncthreads();   // drains glds for buf[cur]; all waves done with buf[cur^1]

        const int kn = k0 + BK;
        if (kn < K_DIM) {  // prefetch next tile, in flight during compute
            const int nb = (cur ^ 1);
            load_lds16(ga0 + kn, As + nb * ATILE + la0);
            load_lds16(ga1 + kn, As + nb * ATILE + la1);
            load_lds16(gb0 + kn, Bs + nb * BTILE + la0);
            load_lds16(gb1 + kn, Bs + nb * BTILE + la1);
        }

        const int8_t* Ab = As + cur * ATILE;
        const int8_t* Bb = Bs + cur * BTILE;

        // Fragment reads: phys colgroup cp = (kstep*2 + hi) ^ swz; row&7 == l32&7
        // cancels the staging XOR -> identity k-chunks (bytes kstep*32+hi*16).
        int4v af[2][4], bf[4];
#pragma unroll
        for (int ks = 0; ks < 4; ks++) {
            const int cp = ((ks * 2 + hi) ^ swz) * 16;
            af[0][ks] = *(const int4v*)(Ab + (wm + l32) * BK + cp);
            af[1][ks] = *(const int4v*)(Ab + (wm + 32 + l32) * BK + cp);
            bf[ks]    = *(const int4v*)(Bb + (wn + l32) * BK + cp);
        }
#pragma unroll
        for (int ks = 0; ks < 4; ks++) {
            acc[0] = __builtin_amdgcn_mfma_i32_32x32x32_i8(af[0][ks], bf[ks], acc[0], 0, 0, 0);
            acc[1] = __builtin_amdgcn_mfma_i32_32x32x32_i8(af[1][ks], bf[ks], acc[1], 0, 0, 0);
        }
    }

    // Epilogue. 32x32 C/D layout (verified, dtype-independent):
    // col = lane&31, row = (reg&3) + 8*(reg>>2) + 4*(lane>>5).
    const int col = bn * BN + wn + l32;
    const float s = scales[col];
    const float b = bias[col];

#pragma unroll
    for (int t = 0; t < 2; t++) {
        const int rbase = bm * BM + wm + t * 32 + 4 * hi;
#pragma unroll
        for (int reg = 0; reg < 16; reg++) {
            const int row = rbase + (reg & 3) + 8 * (reg >> 2);
            C[(size_t)row * N_DIM + col] =
                (float)acc[t][reg] * (sx[row] * s) + b;
        }
    }
}

// ---------- launch ----------

extern "C" void kernel_launch(void* const* d_in, const int* in_sizes, int n_in,
                              void* d_out, int out_size, void* d_ws, size_t ws_size,
                              hipStream_t stream) {
    const float* x      = (const float*)d_in[0];   // [2,1024,4096] fp32
    const int*   w      = (const int*)d_in[1];     // [4096,4096] int, values in [-128,127]
    const float* scales = (const float*)d_in[2];   // [4096]
    const float* bias   = (const float*)d_in[3];   // [4096]
    float*       out    = (float*)d_out;           // [2,1024,4096] fp32

    int8_t* Aq = (int8_t*)d_ws;                                        // 8 MiB
    int8_t* Bq = (int8_t*)d_ws + (size_t)M_DIM * K_DIM;                // 16 MiB
    float*  sx = (float*)((int8_t*)d_ws + (size_t)(M_DIM + N_DIM) * K_DIM); // 8 KiB

    quant_x<<<M_DIM, 256, 0, stream>>>(x, Aq, sx);
    cvt_w8<<<(int)((size_t)N_DIM * K_DIM / 16 / 256), 256, 0, stream>>>(w, Bq);

    dim3 grid(N_DIM / BN, M_DIM / BM);  // (32, 16) = 512 blocks
    gemm_bt_i8<<<grid, 512, 0, stream>>>(Aq, Bq, sx, scales, bias, out);
}